// Round 1
// baseline (1114.005 us; speedup 1.0000x reference)
//
#include <hip/hip_runtime.h>
#include <hip/hip_bf16.h>

#define DEVINL __device__ __forceinline__

constexpr int N  = 50000;
constexpr int E  = 600000;
constexpr int TE = E + N;      // edges + self loops
constexpr int D  = 128;

// ---------- float <-> orderable uint for atomicMax on floats ----------
DEVINL unsigned fkey(float f) {
    unsigned u = __float_as_uint(f);
    return (u & 0x80000000u) ? ~u : (u | 0x80000000u);
}
DEVINL float fdecode(unsigned k) {
    unsigned u = (k & 0x80000000u) ? (k & 0x7FFFFFFFu) : ~k;
    return __uint_as_float(u);
}

DEVINL float lrelu(float x, float s) { return x >= 0.f ? x : s * x; }

// ---------- GEMM: H[v,o] = sum_k Xin[v,k] * W[o,k], optional fused BN+lrelu(0.1) on Xin ----------
// block 256 thr, 16 rows/block, exact: 50000 = 3125*16
__global__ __launch_bounds__(256) void k_gemm(const float* __restrict__ X,
                                              const float* __restrict__ W,
                                              float* __restrict__ H,
                                              const float* __restrict__ ss, // scale[128], shift[128]
                                              int apply_bn) {
    __shared__ float xs[16][128];
    int tid  = threadIdx.x;
    int row0 = blockIdx.x * 16;
    const float4* X4  = (const float4*)(X + (size_t)row0 * D);
    float4*       xs4 = (float4*)(&xs[0][0]);
    #pragma unroll
    for (int i = tid; i < 16 * 32; i += 256) {
        float4 v = X4[i];
        if (apply_bn) {
            int c = (i & 31) * 4;
            float4 sc = *(const float4*)(ss + c);
            float4 sh = *(const float4*)(ss + 128 + c);
            v.x = lrelu(v.x * sc.x + sh.x, 0.1f);
            v.y = lrelu(v.y * sc.y + sh.y, 0.1f);
            v.z = lrelu(v.z * sc.z + sh.z, 0.1f);
            v.w = lrelu(v.w * sc.w + sh.w, 0.1f);
        }
        xs4[i] = v;
    }
    __syncthreads();
    int o  = tid & 127;
    int rg = tid >> 7;            // 0/1 -> rows rg*8 .. rg*8+7
    float acc[8] = {0,0,0,0,0,0,0,0};
    const float4* W4 = (const float4*)(W + (size_t)o * D);
    #pragma unroll
    for (int kk = 0; kk < 32; kk++) {
        float4 wv = W4[kk];
        #pragma unroll
        for (int j = 0; j < 8; j++) {
            float4 xv = *(const float4*)(&xs[rg * 8 + j][kk * 4]);
            acc[j] += xv.x * wv.x + xv.y * wv.y + xv.z * wv.z + xv.w * wv.w;
        }
    }
    #pragma unroll
    for (int j = 0; j < 8; j++)
        H[(size_t)(row0 + rg * 8 + j) * D + o] = acc[j];
}

// ---------- per-node attention dot products: ai=dot(h,att[:128]) (dst role), aj=dot(h,att[128:]) (src role) ----------
__global__ __launch_bounds__(256) void k_attdots(const float* __restrict__ H,
                                                 const float* __restrict__ att,
                                                 float* __restrict__ ai, float* __restrict__ aj) {
    int wid = threadIdx.x >> 6, lane = threadIdx.x & 63;
    int v = blockIdx.x * 4 + wid;
    if (v >= N) return;
    float2 h  = ((const float2*)(H + (size_t)v * D))[lane];
    float2 ad = ((const float2*)att)[lane];
    float2 as = ((const float2*)(att + 128))[lane];
    float pi = h.x * ad.x + h.y * ad.y;
    float pj = h.x * as.x + h.y * as.y;
    #pragma unroll
    for (int off = 32; off; off >>= 1) {
        pi += __shfl_down(pi, off);
        pj += __shfl_down(pj, off);
    }
    if (lane == 0) { ai[v] = pi; aj[v] = pj; }
}

DEVINL void edge_sd(int e, const int* ei, int& s, int& d) {
    if (e < E) { s = ei[e]; d = ei[E + e]; }
    else       { s = d = e - E; }
}

// ---------- per-edge alpha + segment max over src ----------
__global__ __launch_bounds__(256) void k_alpha_max(const int* __restrict__ ei,
                                                   const float* __restrict__ ai,
                                                   const float* __restrict__ aj,
                                                   float* __restrict__ alpha,
                                                   unsigned* __restrict__ amax) {
    int e = blockIdx.x * 256 + threadIdx.x;
    if (e >= TE) return;
    int s, d; edge_sd(e, ei, s, d);
    float a = lrelu(ai[d] + aj[s], 0.2f);
    alpha[e] = a;
    atomicMax(amax + s, fkey(a));
}

// ---------- per-edge exp + segment denom over src ----------
__global__ __launch_bounds__(256) void k_exp_den(const int* __restrict__ ei,
                                                 float* __restrict__ alpha,
                                                 const unsigned* __restrict__ amax,
                                                 float* __restrict__ den) {
    int e = blockIdx.x * 256 + threadIdx.x;
    if (e >= TE) return;
    int s, d; edge_sd(e, ei, s, d);
    float ex = expf(alpha[e] - fdecode(amax[s]));
    alpha[e] = ex;
    atomicAdd(den + s, ex);
}

// ---------- CSR build by dst ----------
__global__ __launch_bounds__(256) void k_deg(const int* __restrict__ ei, int* __restrict__ deg) {
    int e = blockIdx.x * 256 + threadIdx.x;
    if (e >= TE) return;
    int s, d; edge_sd(e, ei, s, d);
    atomicAdd(deg + d, 1);
}

__global__ __launch_bounds__(1024) void k_scan(const int* __restrict__ deg, int* __restrict__ row_ptr) {
    __shared__ int tot[1024];
    const int CHUNK = (N + 1023) / 1024;   // 49
    int t = threadIdx.x;
    int base = t * CHUNK;
    int s = 0;
    for (int i = 0; i < CHUNK; i++) {
        int v = base + i;
        s += (v < N) ? deg[v] : 0;
    }
    tot[t] = s;
    __syncthreads();
    for (int off = 1; off < 1024; off <<= 1) {
        int val = (t >= off) ? tot[t - off] : 0;
        __syncthreads();
        tot[t] += val;
        __syncthreads();
    }
    int run = (t == 0) ? 0 : tot[t - 1];
    for (int i = 0; i < CHUNK; i++) {
        int v = base + i;
        if (v < N) { row_ptr[v] = run; run += deg[v]; }
    }
    if (t == 1023) row_ptr[N] = run;
}

__global__ __launch_bounds__(256) void k_fill(const int* __restrict__ ei,
                                              const int* __restrict__ row_ptr,
                                              int* __restrict__ fill, int* __restrict__ perm) {
    int e = blockIdx.x * 256 + threadIdx.x;
    if (e >= TE) return;
    int s, d; edge_sd(e, ei, s, d);
    int pos = atomicAdd(fill + d, 1);
    perm[row_ptr[d] + pos] = e;
}

// ---------- aggregation: wave per dst node, O[v] = relu(sum_e w_e * H[src_e] + b) ----------
__global__ __launch_bounds__(256) void k_aggregate(const int* __restrict__ row_ptr,
                                                   const int* __restrict__ perm,
                                                   const int* __restrict__ ei,
                                                   const float* __restrict__ alpha,
                                                   const float* __restrict__ den,
                                                   const float* __restrict__ H,
                                                   const float* __restrict__ bvec,
                                                   float* __restrict__ O) {
    int wid = threadIdx.x >> 6, lane = threadIdx.x & 63;
    int v = blockIdx.x * 4 + wid;
    if (v >= N) return;
    int beg = row_ptr[v], end = row_ptr[v + 1];
    float a0 = 0.f, a1 = 0.f;
    for (int idx = beg; idx < end; idx++) {
        int e = perm[idx];
        int s, d; edge_sd(e, ei, s, d);
        float w = alpha[e] / (den[s] + 1e-16f);
        float2 h = ((const float2*)(H + (size_t)s * D))[lane];
        a0 += w * h.x;
        a1 += w * h.y;
    }
    float2 b = ((const float2*)bvec)[lane];
    a0 = fmaxf(a0 + b.x, 0.f);
    a1 = fmaxf(a1 + b.y, 0.f);
    ((float2*)(O + (size_t)v * D))[lane] = make_float2(a0, a1);
}

// ---------- BN column stats ----------
__global__ __launch_bounds__(256) void k_stats(const float* __restrict__ O,
                                               float* __restrict__ colsum, float* __restrict__ colsq) {
    int c = threadIdx.x & 127, rg = threadIdx.x >> 7;
    float s = 0.f, q = 0.f;
    for (int v = blockIdx.x * 2 + rg; v < N; v += gridDim.x * 2) {
        float val = O[(size_t)v * D + c];
        s += val;
        q += val * val;
    }
    __shared__ float ls[256], lq[256];
    ls[threadIdx.x] = s; lq[threadIdx.x] = q;
    __syncthreads();
    if (threadIdx.x < 128) {
        s = ls[threadIdx.x] + ls[threadIdx.x + 128];
        q = lq[threadIdx.x] + lq[threadIdx.x + 128];
        atomicAdd(colsum + c, s);
        atomicAdd(colsq + c, q);
    }
}

__global__ __launch_bounds__(128) void k_bnfinal(const float* __restrict__ colsum,
                                                 const float* __restrict__ colsq,
                                                 const float* __restrict__ g,
                                                 const float* __restrict__ be,
                                                 float* __restrict__ ss) {
    int c = threadIdx.x;
    float mean = colsum[c] / (float)N;
    float var  = colsq[c] / (float)N - mean * mean;
    float scale = g[c] * rsqrtf(var + 1e-5f);
    ss[c] = scale;
    ss[128 + c] = be[c] - mean * scale;
}

// ---------- decoder ----------
__global__ __launch_bounds__(256) void k_T(const float* __restrict__ P1, const float* __restrict__ P2,
                                           float* __restrict__ T) {
    int t = blockIdx.x * 256 + threadIdx.x;
    if (t >= 128 * 64) return;
    int i = t >> 6, d = t & 63;
    float s = 0.f;
    #pragma unroll 8
    for (int k = 0; k < 64; k++) s += P1[i * 64 + k] * P2[k * 64 + d];
    T[t] = s;
}

__global__ __launch_bounds__(256) void k_M(const float* __restrict__ T, const float* __restrict__ P1,
                                           float* __restrict__ M) {
    int t = blockIdx.x * 256 + threadIdx.x;
    if (t >= 128 * 128) return;
    int i = t >> 7, j = t & 127;
    float s = 0.f;
    #pragma unroll 8
    for (int d = 0; d < 64; d++) s += T[i * 64 + d] * P1[j * 64 + d];
    M[t] = s;
}

__global__ __launch_bounds__(128) void k_pred(const float* __restrict__ O,
                                              const float* __restrict__ ss,
                                              const int* __restrict__ drug,
                                              const float* __restrict__ M,
                                              float* __restrict__ out) {
    int b = blockIdx.x, i = threadIdx.x;
    __shared__ float av[128], bv[128];
    int ia = drug[b * 2] - 1, ib = drug[b * 2 + 1] - 1;
    float sc = ss[i], sh = ss[128 + i];
    av[i] = lrelu(O[(size_t)ia * D + i] * sc + sh, 0.1f);
    bv[i] = lrelu(O[(size_t)ib * D + i] * sc + sh, 0.1f);
    __syncthreads();
    float u = 0.f;
    #pragma unroll 8
    for (int j = 0; j < 128; j++) u += M[i * 128 + j] * bv[j];
    float val = av[i] * u;
    #pragma unroll
    for (int off = 32; off; off >>= 1) val += __shfl_down(val, off);
    __shared__ float red[2];
    if ((i & 63) == 0) red[i >> 6] = val;
    __syncthreads();
    if (i == 0) out[b] = red[0] + red[1];
}

extern "C" void kernel_launch(void* const* d_in, const int* in_sizes, int n_in,
                              void* d_out, int out_size, void* d_ws, size_t ws_size,
                              hipStream_t stream) {
    const float* x    = (const float*)d_in[0];
    const int*   ei   = (const int*)  d_in[1];
    const int*   drug = (const int*)  d_in[2];
    const float* W[3]   = {(const float*)d_in[3], (const float*)d_in[8],  (const float*)d_in[13]};
    const float* att[3] = {(const float*)d_in[4], (const float*)d_in[9],  (const float*)d_in[14]};
    const float* bb[3]  = {(const float*)d_in[5], (const float*)d_in[10], (const float*)d_in[15]};
    const float* gg[3]  = {(const float*)d_in[6], (const float*)d_in[11], (const float*)d_in[16]};
    const float* be[3]  = {(const float*)d_in[7], (const float*)d_in[12], (const float*)d_in[17]};
    const float* P1 = (const float*)d_in[18];
    const float* P2 = (const float*)d_in[19];

    float* ws = (float*)d_ws;
    size_t o_H      = 0;
    size_t o_O      = o_H + (size_t)N * D;
    size_t o_ai     = o_O + (size_t)N * D;
    size_t o_aj     = o_ai + N;
    size_t o_amax   = o_aj + N;        // uint, contiguous with den for one memset
    size_t o_den    = o_amax + N;
    size_t o_alpha  = o_den + N;
    size_t o_deg    = o_alpha + TE;    // int
    size_t o_fill   = o_deg + N;       // int
    size_t o_rowptr = o_fill + N;      // int, N+1 (padded to N+8)
    size_t o_perm   = o_rowptr + N + 8;// int, TE
    size_t o_colsum = o_perm + TE;     // 128
    size_t o_colsq  = o_colsum + 128;  // 128 (contiguous memset with colsum)
    size_t o_ss     = o_colsq + 128;   // 256
    size_t o_T      = o_ss + 256;      // 128*64
    size_t o_Mm     = o_T + 128 * 64;  // 128*128

    float*    Hb    = ws + o_H;
    float*    Ob    = ws + o_O;
    float*    ai    = ws + o_ai;
    float*    aj    = ws + o_aj;
    unsigned* amax  = (unsigned*)(ws + o_amax);
    float*    den   = ws + o_den;
    float*    alpha = ws + o_alpha;
    int*      deg   = (int*)(ws + o_deg);
    int*      fill  = (int*)(ws + o_fill);
    int*      rowp  = (int*)(ws + o_rowptr);
    int*      perm  = (int*)(ws + o_perm);
    float*    csum  = ws + o_colsum;
    float*    csq   = ws + o_colsq;
    float*    ss    = ws + o_ss;
    float*    Tm    = ws + o_T;
    float*    Mm    = ws + o_Mm;

    const int EB = (TE + 255) / 256;   // 2540 blocks for edge kernels

    // ---- CSR by dst (graph identical for all 3 layers) ----
    hipMemsetAsync(deg, 0, (size_t)N * 4, stream);
    k_deg<<<EB, 256, 0, stream>>>(ei, deg);
    k_scan<<<1, 1024, 0, stream>>>(deg, rowp);
    hipMemsetAsync(fill, 0, (size_t)N * 4, stream);
    k_fill<<<EB, 256, 0, stream>>>(ei, rowp, fill, perm);

    // ---- 3 GAT layers ----
    for (int l = 0; l < 3; l++) {
        const float* Xin = (l == 0) ? x : Ob;
        k_gemm<<<N / 16, 256, 0, stream>>>(Xin, W[l], Hb, ss, l > 0 ? 1 : 0);
        k_attdots<<<(N + 3) / 4, 256, 0, stream>>>(Hb, att[l], ai, aj);
        hipMemsetAsync(amax, 0, (size_t)2 * N * 4, stream);  // amax keys + den
        k_alpha_max<<<EB, 256, 0, stream>>>(ei, ai, aj, alpha, amax);
        k_exp_den<<<EB, 256, 0, stream>>>(ei, alpha, amax, den);
        k_aggregate<<<(N + 3) / 4, 256, 0, stream>>>(rowp, perm, ei, alpha, den, Hb, bb[l], Ob);
        hipMemsetAsync(csum, 0, 256 * 4, stream);            // colsum + colsq
        k_stats<<<256, 256, 0, stream>>>(Ob, csum, csq);
        k_bnfinal<<<1, 128, 0, stream>>>(csum, csq, gg[l], be[l], ss);
    }

    // ---- decoder ----
    k_T<<<32, 256, 0, stream>>>(P1, P2, Tm);
    k_M<<<64, 256, 0, stream>>>(Tm, P1, Mm);
    k_pred<<<1024, 128, 0, stream>>>(Ob, ss, drug, Mm, (float*)d_out);
}

// Round 2
// 939.741 us; speedup vs baseline: 1.1854x; 1.1854x over previous
//
#include <hip/hip_runtime.h>
#include <hip/hip_bf16.h>

#define DEVINL __device__ __forceinline__

constexpr int N  = 50000;
constexpr int E  = 600000;
constexpr int TE = E + N;      // edges + self loops
constexpr int D  = 128;

// ---------- float <-> orderable uint for atomicMax on floats ----------
DEVINL unsigned fkey(float f) {
    unsigned u = __float_as_uint(f);
    return (u & 0x80000000u) ? ~u : (u | 0x80000000u);
}
DEVINL float fdecode(unsigned k) {
    unsigned u = (k & 0x80000000u) ? (k & 0x7FFFFFFFu) : ~k;
    return __uint_as_float(u);
}

DEVINL float lrelu(float x, float s) { return x >= 0.f ? x : s * x; }

// ---------- GEMM: H[v,o] = sum_k Xin[v,k] * W[o,k], optional fused BN+lrelu(0.1) on Xin ----------
__global__ __launch_bounds__(256) void k_gemm(const float* __restrict__ X,
                                              const float* __restrict__ W,
                                              float* __restrict__ H,
                                              const float* __restrict__ ss, // scale[128], shift[128]
                                              int apply_bn) {
    __shared__ float xs[16][128];
    int tid  = threadIdx.x;
    int row0 = blockIdx.x * 16;
    const float4* X4  = (const float4*)(X + (size_t)row0 * D);
    float4*       xs4 = (float4*)(&xs[0][0]);
    #pragma unroll
    for (int i = tid; i < 16 * 32; i += 256) {
        float4 v = X4[i];
        if (apply_bn) {
            int c = (i & 31) * 4;
            float4 sc = *(const float4*)(ss + c);
            float4 sh = *(const float4*)(ss + 128 + c);
            v.x = lrelu(v.x * sc.x + sh.x, 0.1f);
            v.y = lrelu(v.y * sc.y + sh.y, 0.1f);
            v.z = lrelu(v.z * sc.z + sh.z, 0.1f);
            v.w = lrelu(v.w * sc.w + sh.w, 0.1f);
        }
        xs4[i] = v;
    }
    __syncthreads();
    int o  = tid & 127;
    int rg = tid >> 7;
    float acc[8] = {0,0,0,0,0,0,0,0};
    const float4* W4 = (const float4*)(W + (size_t)o * D);
    #pragma unroll
    for (int kk = 0; kk < 32; kk++) {
        float4 wv = W4[kk];
        #pragma unroll
        for (int j = 0; j < 8; j++) {
            float4 xv = *(const float4*)(&xs[rg * 8 + j][kk * 4]);
            acc[j] += xv.x * wv.x + xv.y * wv.y + xv.z * wv.z + xv.w * wv.w;
        }
    }
    #pragma unroll
    for (int j = 0; j < 8; j++)
        H[(size_t)(row0 + rg * 8 + j) * D + o] = acc[j];
}

// ---------- per-node attention dot products ----------
__global__ __launch_bounds__(256) void k_attdots(const float* __restrict__ H,
                                                 const float* __restrict__ att,
                                                 float* __restrict__ ai, float* __restrict__ aj) {
    int wid = threadIdx.x >> 6, lane = threadIdx.x & 63;
    int v = blockIdx.x * 4 + wid;
    if (v >= N) return;
    float2 h  = ((const float2*)(H + (size_t)v * D))[lane];
    float2 ad = ((const float2*)att)[lane];
    float2 as = ((const float2*)(att + 128))[lane];
    float pi = h.x * ad.x + h.y * ad.y;
    float pj = h.x * as.x + h.y * as.y;
    #pragma unroll
    for (int off = 32; off; off >>= 1) {
        pi += __shfl_down(pi, off);
        pj += __shfl_down(pj, off);
    }
    if (lane == 0) { ai[v] = pi; aj[v] = pj; }
}

DEVINL void edge_sd(int e, const int* ei, int& s, int& d) {
    if (e < E) { s = ei[e]; d = ei[E + e]; }
    else       { s = d = e - E; }
}

// ---------- CSR build by dst (once; graph shared across layers) ----------
__global__ __launch_bounds__(256) void k_deg(const int* __restrict__ ei, int* __restrict__ deg) {
    int e = blockIdx.x * 256 + threadIdx.x;
    if (e >= TE) return;
    int s, d; edge_sd(e, ei, s, d);
    atomicAdd(deg + d, 1);
}

__global__ __launch_bounds__(1024) void k_scan(const int* __restrict__ deg, int* __restrict__ row_ptr) {
    __shared__ int tot[1024];
    const int CHUNK = (N + 1023) / 1024;
    int t = threadIdx.x;
    int base = t * CHUNK;
    int s = 0;
    for (int i = 0; i < CHUNK; i++) {
        int v = base + i;
        s += (v < N) ? deg[v] : 0;
    }
    tot[t] = s;
    __syncthreads();
    for (int off = 1; off < 1024; off <<= 1) {
        int val = (t >= off) ? tot[t - off] : 0;
        __syncthreads();
        tot[t] += val;
        __syncthreads();
    }
    int run = (t == 0) ? 0 : tot[t - 1];
    for (int i = 0; i < CHUNK; i++) {
        int v = base + i;
        if (v < N) { row_ptr[v] = run; run += deg[v]; }
    }
    if (t == 1023) row_ptr[N] = run;
}

__global__ __launch_bounds__(256) void k_fill(const int* __restrict__ ei,
                                              const int* __restrict__ row_ptr,
                                              int* __restrict__ fill,
                                              int* __restrict__ src_csr,
                                              int* __restrict__ dst_csr) {
    int e = blockIdx.x * 256 + threadIdx.x;
    if (e >= TE) return;
    int s, d; edge_sd(e, ei, s, d);
    int pos = atomicAdd(fill + d, 1);
    int p = row_ptr[d] + pos;
    src_csr[p] = s;
    dst_csr[p] = d;
}

// ---------- per-edge (CSR order) alpha + segment max over src ----------
__global__ __launch_bounds__(256) void k_alpha_max(const int* __restrict__ src_csr,
                                                   const int* __restrict__ dst_csr,
                                                   const float* __restrict__ ai,
                                                   const float* __restrict__ aj,
                                                   float* __restrict__ alpha,
                                                   unsigned* __restrict__ amax) {
    int idx = blockIdx.x * 256 + threadIdx.x;
    if (idx >= TE) return;
    int s = src_csr[idx], d = dst_csr[idx];
    float a = lrelu(ai[d] + aj[s], 0.2f);
    alpha[idx] = a;
    atomicMax(amax + s, fkey(a));
}

// ---------- per-edge (CSR order) exp + segment denom over src ----------
__global__ __launch_bounds__(256) void k_exp_den(const int* __restrict__ src_csr,
                                                 float* __restrict__ alpha,
                                                 const unsigned* __restrict__ amax,
                                                 float* __restrict__ den) {
    int idx = blockIdx.x * 256 + threadIdx.x;
    if (idx >= TE) return;
    int s = src_csr[idx];
    float ex = expf(alpha[idx] - fdecode(amax[s]));
    alpha[idx] = ex;
    atomicAdd(den + s, ex);
}

// ---------- aggregation: wave per dst node, 4-edge unroll ----------
__global__ __launch_bounds__(256) void k_aggregate(const int* __restrict__ row_ptr,
                                                   const int* __restrict__ src_csr,
                                                   const float* __restrict__ alpha,
                                                   const float* __restrict__ den,
                                                   const float* __restrict__ H,
                                                   const float* __restrict__ bvec,
                                                   float* __restrict__ O) {
    int wid = threadIdx.x >> 6, lane = threadIdx.x & 63;
    int v = blockIdx.x * 4 + wid;
    if (v >= N) return;
    int beg = row_ptr[v], end = row_ptr[v + 1];
    const float2* H2 = (const float2*)H;
    float a0 = 0.f, a1 = 0.f;
    int idx = beg;
    for (; idx + 4 <= end; idx += 4) {
        int s0 = src_csr[idx + 0], s1 = src_csr[idx + 1];
        int s2 = src_csr[idx + 2], s3 = src_csr[idx + 3];
        float w0 = alpha[idx + 0] / (den[s0] + 1e-16f);
        float w1 = alpha[idx + 1] / (den[s1] + 1e-16f);
        float w2 = alpha[idx + 2] / (den[s2] + 1e-16f);
        float w3 = alpha[idx + 3] / (den[s3] + 1e-16f);
        float2 h0 = H2[(size_t)s0 * 64 + lane];
        float2 h1 = H2[(size_t)s1 * 64 + lane];
        float2 h2 = H2[(size_t)s2 * 64 + lane];
        float2 h3 = H2[(size_t)s3 * 64 + lane];
        a0 += w0 * h0.x + w1 * h1.x + w2 * h2.x + w3 * h3.x;
        a1 += w0 * h0.y + w1 * h1.y + w2 * h2.y + w3 * h3.y;
    }
    for (; idx < end; idx++) {
        int s = src_csr[idx];
        float w = alpha[idx] / (den[s] + 1e-16f);
        float2 h = H2[(size_t)s * 64 + lane];
        a0 += w * h.x;
        a1 += w * h.y;
    }
    float2 b = ((const float2*)bvec)[lane];
    a0 = fmaxf(a0 + b.x, 0.f);
    a1 = fmaxf(a1 + b.y, 0.f);
    ((float2*)(O + (size_t)v * D))[lane] = make_float2(a0, a1);
}

// ---------- BN column stats ----------
__global__ __launch_bounds__(256) void k_stats(const float* __restrict__ O,
                                               float* __restrict__ colsum, float* __restrict__ colsq) {
    int c = threadIdx.x & 127, rg = threadIdx.x >> 7;
    float s = 0.f, q = 0.f;
    for (int v = blockIdx.x * 2 + rg; v < N; v += gridDim.x * 2) {
        float val = O[(size_t)v * D + c];
        s += val;
        q += val * val;
    }
    __shared__ float ls[256], lq[256];
    ls[threadIdx.x] = s; lq[threadIdx.x] = q;
    __syncthreads();
    if (threadIdx.x < 128) {
        s = ls[threadIdx.x] + ls[threadIdx.x + 128];
        q = lq[threadIdx.x] + lq[threadIdx.x + 128];
        atomicAdd(colsum + c, s);
        atomicAdd(colsq + c, q);
    }
}

__global__ __launch_bounds__(128) void k_bnfinal(const float* __restrict__ colsum,
                                                 const float* __restrict__ colsq,
                                                 const float* __restrict__ g,
                                                 const float* __restrict__ be,
                                                 float* __restrict__ ss) {
    int c = threadIdx.x;
    float mean = colsum[c] / (float)N;
    float var  = colsq[c] / (float)N - mean * mean;
    float scale = g[c] * rsqrtf(var + 1e-5f);
    ss[c] = scale;
    ss[128 + c] = be[c] - mean * scale;
}

// ---------- decoder ----------
__global__ __launch_bounds__(256) void k_T(const float* __restrict__ P1, const float* __restrict__ P2,
                                           float* __restrict__ T) {
    int t = blockIdx.x * 256 + threadIdx.x;
    if (t >= 128 * 64) return;
    int i = t >> 6, d = t & 63;
    float s = 0.f;
    #pragma unroll 8
    for (int k = 0; k < 64; k++) s += P1[i * 64 + k] * P2[k * 64 + d];
    T[t] = s;
}

__global__ __launch_bounds__(256) void k_M(const float* __restrict__ T, const float* __restrict__ P1,
                                           float* __restrict__ M) {
    int t = blockIdx.x * 256 + threadIdx.x;
    if (t >= 128 * 128) return;
    int i = t >> 7, j = t & 127;
    float s = 0.f;
    #pragma unroll 8
    for (int d = 0; d < 64; d++) s += T[i * 64 + d] * P1[j * 64 + d];
    M[t] = s;
}

__global__ __launch_bounds__(128) void k_pred(const float* __restrict__ O,
                                              const float* __restrict__ ss,
                                              const int* __restrict__ drug,
                                              const float* __restrict__ M,
                                              float* __restrict__ out) {
    int b = blockIdx.x, i = threadIdx.x;
    __shared__ float av[128], bv[128];
    int ia = drug[b * 2] - 1, ib = drug[b * 2 + 1] - 1;
    float sc = ss[i], sh = ss[128 + i];
    av[i] = lrelu(O[(size_t)ia * D + i] * sc + sh, 0.1f);
    bv[i] = lrelu(O[(size_t)ib * D + i] * sc + sh, 0.1f);
    __syncthreads();
    float u = 0.f;
    #pragma unroll 8
    for (int j = 0; j < 128; j++) u += M[i * 128 + j] * bv[j];
    float val = av[i] * u;
    #pragma unroll
    for (int off = 32; off; off >>= 1) val += __shfl_down(val, off);
    __shared__ float red[2];
    if ((i & 63) == 0) red[i >> 6] = val;
    __syncthreads();
    if (i == 0) out[b] = red[0] + red[1];
}

extern "C" void kernel_launch(void* const* d_in, const int* in_sizes, int n_in,
                              void* d_out, int out_size, void* d_ws, size_t ws_size,
                              hipStream_t stream) {
    const float* x    = (const float*)d_in[0];
    const int*   ei   = (const int*)  d_in[1];
    const int*   drug = (const int*)  d_in[2];
    const float* W[3]   = {(const float*)d_in[3], (const float*)d_in[8],  (const float*)d_in[13]};
    const float* att[3] = {(const float*)d_in[4], (const float*)d_in[9],  (const float*)d_in[14]};
    const float* bb[3]  = {(const float*)d_in[5], (const float*)d_in[10], (const float*)d_in[15]};
    const float* gg[3]  = {(const float*)d_in[6], (const float*)d_in[11], (const float*)d_in[16]};
    const float* be[3]  = {(const float*)d_in[7], (const float*)d_in[12], (const float*)d_in[17]};
    const float* P1 = (const float*)d_in[18];
    const float* P2 = (const float*)d_in[19];

    float* ws = (float*)d_ws;
    size_t o_H      = 0;
    size_t o_O      = o_H + (size_t)N * D;
    size_t o_ai     = o_O + (size_t)N * D;
    size_t o_aj     = o_ai + N;
    size_t o_amax   = o_aj + N;        // uint, contiguous with den for one memset
    size_t o_den    = o_amax + N;
    size_t o_alpha  = o_den + N;
    size_t o_deg    = o_alpha + TE;    // int
    size_t o_fill   = o_deg + N;       // int
    size_t o_rowptr = o_fill + N;      // int, N+1 (pad 8)
    size_t o_src    = o_rowptr + N + 8;// int, TE
    size_t o_dst    = o_src + TE;      // int, TE
    size_t o_colsum = o_dst + TE;      // 128
    size_t o_colsq  = o_colsum + 128;  // 128
    size_t o_ss     = o_colsq + 128;   // 256
    size_t o_T      = o_ss + 256;      // 128*64
    size_t o_Mm     = o_T + 128 * 64;  // 128*128

    float*    Hb    = ws + o_H;
    float*    Ob    = ws + o_O;
    float*    ai    = ws + o_ai;
    float*    aj    = ws + o_aj;
    unsigned* amax  = (unsigned*)(ws + o_amax);
    float*    den   = ws + o_den;
    float*    alpha = ws + o_alpha;
    int*      deg   = (int*)(ws + o_deg);
    int*      fill  = (int*)(ws + o_fill);
    int*      rowp  = (int*)(ws + o_rowptr);
    int*      srcc  = (int*)(ws + o_src);
    int*      dstc  = (int*)(ws + o_dst);
    float*    csum  = ws + o_colsum;
    float*    csq   = ws + o_colsq;
    float*    ss    = ws + o_ss;
    float*    Tm    = ws + o_T;
    float*    Mm    = ws + o_Mm;

    const int EB = (TE + 255) / 256;

    // ---- CSR by dst ----
    hipMemsetAsync(deg, 0, (size_t)N * 4, stream);
    k_deg<<<EB, 256, 0, stream>>>(ei, deg);
    k_scan<<<1, 1024, 0, stream>>>(deg, rowp);
    hipMemsetAsync(fill, 0, (size_t)N * 4, stream);
    k_fill<<<EB, 256, 0, stream>>>(ei, rowp, fill, srcc, dstc);

    // ---- 3 GAT layers ----
    for (int l = 0; l < 3; l++) {
        const float* Xin = (l == 0) ? x : Ob;
        k_gemm<<<N / 16, 256, 0, stream>>>(Xin, W[l], Hb, ss, l > 0 ? 1 : 0);
        k_attdots<<<(N + 3) / 4, 256, 0, stream>>>(Hb, att[l], ai, aj);
        hipMemsetAsync(amax, 0, (size_t)2 * N * 4, stream);  // amax keys + den
        k_alpha_max<<<EB, 256, 0, stream>>>(srcc, dstc, ai, aj, alpha, amax);
        k_exp_den<<<EB, 256, 0, stream>>>(srcc, alpha, amax, den);
        k_aggregate<<<(N + 3) / 4, 256, 0, stream>>>(rowp, srcc, alpha, den, Hb, bb[l], Ob);
        hipMemsetAsync(csum, 0, 256 * 4, stream);            // colsum + colsq
        k_stats<<<256, 256, 0, stream>>>(Ob, csum, csq);
        k_bnfinal<<<1, 128, 0, stream>>>(csum, csq, gg[l], be[l], ss);
    }

    // ---- decoder ----
    k_T<<<32, 256, 0, stream>>>(P1, P2, Tm);
    k_M<<<64, 256, 0, stream>>>(Tm, P1, Mm);
    k_pred<<<1024, 128, 0, stream>>>(Ob, ss, drug, Mm, (float*)d_out);
}

// Round 3
// 877.245 us; speedup vs baseline: 1.2699x; 1.0712x over previous
//
#include <hip/hip_runtime.h>
#include <hip/hip_bf16.h>

#define DEVINL __device__ __forceinline__

constexpr int N  = 50000;
constexpr int E  = 600000;
constexpr int TE = E + N;      // edges + self loops
constexpr int D  = 128;
constexpr int SCAN_B = (N + 255) / 256;   // 196 blocks for hierarchical scan

// ---------- float <-> orderable uint for atomicMax on floats ----------
DEVINL unsigned fkey(float f) {
    unsigned u = __float_as_uint(f);
    return (u & 0x80000000u) ? ~u : (u | 0x80000000u);
}
DEVINL float fdecode(unsigned k) {
    unsigned u = (k & 0x80000000u) ? (k & 0x7FFFFFFFu) : ~k;
    return __uint_as_float(u);
}

DEVINL float lrelu(float x, float s) { return x >= 0.f ? x : s * x; }

// ---------- GEMM: H[v,o] = sum_k Xin[v,k] * W[o,k], optional fused BN+lrelu(0.1) on Xin ----------
__global__ __launch_bounds__(256) void k_gemm(const float* __restrict__ X,
                                              const float* __restrict__ W,
                                              float* __restrict__ H,
                                              const float* __restrict__ ss, // scale[128], shift[128]
                                              int apply_bn) {
    __shared__ float xs[16][128];
    int tid  = threadIdx.x;
    int row0 = blockIdx.x * 16;
    const float4* X4  = (const float4*)(X + (size_t)row0 * D);
    float4*       xs4 = (float4*)(&xs[0][0]);
    #pragma unroll
    for (int i = tid; i < 16 * 32; i += 256) {
        float4 v = X4[i];
        if (apply_bn) {
            int c = (i & 31) * 4;
            float4 sc = *(const float4*)(ss + c);
            float4 sh = *(const float4*)(ss + 128 + c);
            v.x = lrelu(v.x * sc.x + sh.x, 0.1f);
            v.y = lrelu(v.y * sc.y + sh.y, 0.1f);
            v.z = lrelu(v.z * sc.z + sh.z, 0.1f);
            v.w = lrelu(v.w * sc.w + sh.w, 0.1f);
        }
        xs4[i] = v;
    }
    __syncthreads();
    int o  = tid & 127;
    int rg = tid >> 7;
    float acc[8] = {0,0,0,0,0,0,0,0};
    const float4* W4 = (const float4*)(W + (size_t)o * D);
    #pragma unroll
    for (int kk = 0; kk < 32; kk++) {
        float4 wv = W4[kk];
        #pragma unroll
        for (int j = 0; j < 8; j++) {
            float4 xv = *(const float4*)(&xs[rg * 8 + j][kk * 4]);
            acc[j] += xv.x * wv.x + xv.y * wv.y + xv.z * wv.z + xv.w * wv.w;
        }
    }
    #pragma unroll
    for (int j = 0; j < 8; j++)
        H[(size_t)(row0 + rg * 8 + j) * D + o] = acc[j];
}

// ---------- per-node attention dot products ----------
__global__ __launch_bounds__(256) void k_attdots(const float* __restrict__ H,
                                                 const float* __restrict__ att,
                                                 float* __restrict__ ai, float* __restrict__ aj) {
    int wid = threadIdx.x >> 6, lane = threadIdx.x & 63;
    int v = blockIdx.x * 4 + wid;
    if (v >= N) return;
    float2 h  = ((const float2*)(H + (size_t)v * D))[lane];
    float2 ad = ((const float2*)att)[lane];
    float2 as = ((const float2*)(att + 128))[lane];
    float pi = h.x * ad.x + h.y * ad.y;
    float pj = h.x * as.x + h.y * as.y;
    #pragma unroll
    for (int off = 32; off; off >>= 1) {
        pi += __shfl_down(pi, off);
        pj += __shfl_down(pj, off);
    }
    if (lane == 0) { ai[v] = pi; aj[v] = pj; }
}

DEVINL void edge_sd(int e, const int* ei, int& s, int& d) {
    if (e < E) { s = ei[e]; d = ei[E + e]; }
    else       { s = d = e - E; }
}

// ---------- CSR build by dst (once; graph shared across layers) ----------
__global__ __launch_bounds__(256) void k_deg(const int* __restrict__ ei, int* __restrict__ deg) {
    int e = blockIdx.x * 256 + threadIdx.x;
    if (e >= TE) return;
    int s, d; edge_sd(e, ei, s, d);
    atomicAdd(deg + d, 1);
}

// ---- hierarchical scan: stage A — per-block sums ----
__global__ __launch_bounds__(256) void k_scan1(const int* __restrict__ deg, int* __restrict__ bsum) {
    __shared__ int red[256];
    int t = threadIdx.x;
    int v = blockIdx.x * 256 + t;
    red[t] = (v < N) ? deg[v] : 0;
    __syncthreads();
    #pragma unroll
    for (int off = 128; off; off >>= 1) {
        if (t < off) red[t] += red[t + off];
        __syncthreads();
    }
    if (t == 0) bsum[blockIdx.x] = red[0];
}

// ---- stage B — exclusive scan of block sums (196 entries, 1 block) ----
__global__ __launch_bounds__(256) void k_scan2(const int* __restrict__ bsum,
                                               int* __restrict__ boff, int* __restrict__ row_ptr) {
    __shared__ int sc[256];
    int t = threadIdx.x;
    int v = (t < SCAN_B) ? bsum[t] : 0;
    sc[t] = v;
    __syncthreads();
    #pragma unroll
    for (int off = 1; off < 256; off <<= 1) {
        int add = (t >= off) ? sc[t - off] : 0;
        __syncthreads();
        sc[t] += add;
        __syncthreads();
    }
    if (t < SCAN_B) boff[t] = sc[t] - v;       // exclusive
    if (t == SCAN_B - 1) row_ptr[N] = sc[t];   // total = TE
}

// ---- stage C — block-local exclusive scan + block offset ----
__global__ __launch_bounds__(256) void k_scan3(const int* __restrict__ deg,
                                               const int* __restrict__ boff,
                                               int* __restrict__ row_ptr) {
    __shared__ int sc[256];
    int t = threadIdx.x;
    int v = blockIdx.x * 256 + t;
    int d = (v < N) ? deg[v] : 0;
    sc[t] = d;
    __syncthreads();
    #pragma unroll
    for (int off = 1; off < 256; off <<= 1) {
        int add = (t >= off) ? sc[t - off] : 0;
        __syncthreads();
        sc[t] += add;
        __syncthreads();
    }
    if (v < N) row_ptr[v] = boff[blockIdx.x] + sc[t] - d;
}

__global__ __launch_bounds__(256) void k_fill(const int* __restrict__ ei,
                                              const int* __restrict__ row_ptr,
                                              int* __restrict__ fill,
                                              int* __restrict__ src_csr,
                                              int* __restrict__ dst_csr) {
    int e = blockIdx.x * 256 + threadIdx.x;
    if (e >= TE) return;
    int s, d; edge_sd(e, ei, s, d);
    int pos = atomicAdd(fill + d, 1);
    int p = row_ptr[d] + pos;
    src_csr[p] = s;
    dst_csr[p] = d;
}

// ---------- per-edge (CSR order) alpha + segment max over src ----------
__global__ __launch_bounds__(256) void k_alpha_max(const int* __restrict__ src_csr,
                                                   const int* __restrict__ dst_csr,
                                                   const float* __restrict__ ai,
                                                   const float* __restrict__ aj,
                                                   float* __restrict__ alpha,
                                                   unsigned* __restrict__ amax) {
    int idx = blockIdx.x * 256 + threadIdx.x;
    if (idx >= TE) return;
    int s = src_csr[idx], d = dst_csr[idx];
    float a = lrelu(ai[d] + aj[s], 0.2f);
    alpha[idx] = a;
    atomicMax(amax + s, fkey(a));
}

// ---------- per-edge (CSR order) exp + segment denom over src ----------
__global__ __launch_bounds__(256) void k_exp_den(const int* __restrict__ src_csr,
                                                 float* __restrict__ alpha,
                                                 const unsigned* __restrict__ amax,
                                                 float* __restrict__ den) {
    int idx = blockIdx.x * 256 + threadIdx.x;
    if (idx >= TE) return;
    int s = src_csr[idx];
    float ex = expf(alpha[idx] - fdecode(amax[s]));
    alpha[idx] = ex;
    atomicAdd(den + s, ex);
}

// ---------- aggregation: wave per dst node, 8-edge unroll ----------
__global__ __launch_bounds__(256) void k_aggregate(const int* __restrict__ row_ptr,
                                                   const int* __restrict__ src_csr,
                                                   const float* __restrict__ alpha,
                                                   const float* __restrict__ den,
                                                   const float* __restrict__ H,
                                                   const float* __restrict__ bvec,
                                                   float* __restrict__ O) {
    int wid = threadIdx.x >> 6, lane = threadIdx.x & 63;
    int v = blockIdx.x * 4 + wid;
    if (v >= N) return;
    int beg = row_ptr[v], end = row_ptr[v + 1];
    const float2* H2 = (const float2*)H;
    float a0 = 0.f, a1 = 0.f;
    int idx = beg;
    for (; idx + 8 <= end; idx += 8) {
        int   s[8];
        float w[8];
        #pragma unroll
        for (int u = 0; u < 8; u++) s[u] = src_csr[idx + u];
        #pragma unroll
        for (int u = 0; u < 8; u++) w[u] = alpha[idx + u] / (den[s[u]] + 1e-16f);
        float2 h[8];
        #pragma unroll
        for (int u = 0; u < 8; u++) h[u] = H2[(size_t)s[u] * 64 + lane];
        #pragma unroll
        for (int u = 0; u < 8; u++) { a0 += w[u] * h[u].x; a1 += w[u] * h[u].y; }
    }
    for (; idx < end; idx++) {
        int s = src_csr[idx];
        float w = alpha[idx] / (den[s] + 1e-16f);
        float2 h = H2[(size_t)s * 64 + lane];
        a0 += w * h.x;
        a1 += w * h.y;
    }
    float2 b = ((const float2*)bvec)[lane];
    a0 = fmaxf(a0 + b.x, 0.f);
    a1 = fmaxf(a1 + b.y, 0.f);
    ((float2*)(O + (size_t)v * D))[lane] = make_float2(a0, a1);
}

// ---------- BN column stats ----------
__global__ __launch_bounds__(256) void k_stats(const float* __restrict__ O,
                                               float* __restrict__ colsum, float* __restrict__ colsq) {
    int c = threadIdx.x & 127, rg = threadIdx.x >> 7;
    float s = 0.f, q = 0.f;
    for (int v = blockIdx.x * 2 + rg; v < N; v += gridDim.x * 2) {
        float val = O[(size_t)v * D + c];
        s += val;
        q += val * val;
    }
    __shared__ float ls[256], lq[256];
    ls[threadIdx.x] = s; lq[threadIdx.x] = q;
    __syncthreads();
    if (threadIdx.x < 128) {
        s = ls[threadIdx.x] + ls[threadIdx.x + 128];
        q = lq[threadIdx.x] + lq[threadIdx.x + 128];
        atomicAdd(colsum + c, s);
        atomicAdd(colsq + c, q);
    }
}

__global__ __launch_bounds__(128) void k_bnfinal(const float* __restrict__ colsum,
                                                 const float* __restrict__ colsq,
                                                 const float* __restrict__ g,
                                                 const float* __restrict__ be,
                                                 float* __restrict__ ss) {
    int c = threadIdx.x;
    float mean = colsum[c] / (float)N;
    float var  = colsq[c] / (float)N - mean * mean;
    float scale = g[c] * rsqrtf(var + 1e-5f);
    ss[c] = scale;
    ss[128 + c] = be[c] - mean * scale;
}

// ---------- decoder ----------
__global__ __launch_bounds__(256) void k_T(const float* __restrict__ P1, const float* __restrict__ P2,
                                           float* __restrict__ T) {
    int t = blockIdx.x * 256 + threadIdx.x;
    if (t >= 128 * 64) return;
    int i = t >> 6, d = t & 63;
    float s = 0.f;
    #pragma unroll 8
    for (int k = 0; k < 64; k++) s += P1[i * 64 + k] * P2[k * 64 + d];
    T[t] = s;
}

__global__ __launch_bounds__(256) void k_M(const float* __restrict__ T, const float* __restrict__ P1,
                                           float* __restrict__ M) {
    int t = blockIdx.x * 256 + threadIdx.x;
    if (t >= 128 * 128) return;
    int i = t >> 7, j = t & 127;
    float s = 0.f;
    #pragma unroll 8
    for (int d = 0; d < 64; d++) s += T[i * 64 + d] * P1[j * 64 + d];
    M[t] = s;
}

__global__ __launch_bounds__(128) void k_pred(const float* __restrict__ O,
                                              const float* __restrict__ ss,
                                              const int* __restrict__ drug,
                                              const float* __restrict__ M,
                                              float* __restrict__ out) {
    int b = blockIdx.x, i = threadIdx.x;
    __shared__ float av[128], bv[128];
    int ia = drug[b * 2] - 1, ib = drug[b * 2 + 1] - 1;
    float sc = ss[i], sh = ss[128 + i];
    av[i] = lrelu(O[(size_t)ia * D + i] * sc + sh, 0.1f);
    bv[i] = lrelu(O[(size_t)ib * D + i] * sc + sh, 0.1f);
    __syncthreads();
    float u = 0.f;
    #pragma unroll 8
    for (int j = 0; j < 128; j++) u += M[i * 128 + j] * bv[j];
    float val = av[i] * u;
    #pragma unroll
    for (int off = 32; off; off >>= 1) val += __shfl_down(val, off);
    __shared__ float red[2];
    if ((i & 63) == 0) red[i >> 6] = val;
    __syncthreads();
    if (i == 0) out[b] = red[0] + red[1];
}

extern "C" void kernel_launch(void* const* d_in, const int* in_sizes, int n_in,
                              void* d_out, int out_size, void* d_ws, size_t ws_size,
                              hipStream_t stream) {
    const float* x    = (const float*)d_in[0];
    const int*   ei   = (const int*)  d_in[1];
    const int*   drug = (const int*)  d_in[2];
    const float* W[3]   = {(const float*)d_in[3], (const float*)d_in[8],  (const float*)d_in[13]};
    const float* att[3] = {(const float*)d_in[4], (const float*)d_in[9],  (const float*)d_in[14]};
    const float* bb[3]  = {(const float*)d_in[5], (const float*)d_in[10], (const float*)d_in[15]};
    const float* gg[3]  = {(const float*)d_in[6], (const float*)d_in[11], (const float*)d_in[16]};
    const float* be[3]  = {(const float*)d_in[7], (const float*)d_in[12], (const float*)d_in[17]};
    const float* P1 = (const float*)d_in[18];
    const float* P2 = (const float*)d_in[19];

    float* ws = (float*)d_ws;
    size_t o_H      = 0;
    size_t o_O      = o_H + (size_t)N * D;
    size_t o_ai     = o_O + (size_t)N * D;
    size_t o_aj     = o_ai + N;
    size_t o_amax   = o_aj + N;        // uint, contiguous with den for one memset
    size_t o_den    = o_amax + N;
    size_t o_alpha  = o_den + N;
    size_t o_deg    = o_alpha + TE;    // int
    size_t o_fill   = o_deg + N;       // int
    size_t o_rowptr = o_fill + N;      // int, N+1 (pad 8)
    size_t o_src    = o_rowptr + N + 8;// int, TE
    size_t o_dst    = o_src + TE;      // int, TE
    size_t o_bsum   = o_dst + TE;      // int, SCAN_B (pad to 256)
    size_t o_boff   = o_bsum + 256;    // int, SCAN_B (pad to 256)
    size_t o_colsum = o_boff + 256;    // 128
    size_t o_colsq  = o_colsum + 128;  // 128
    size_t o_ss     = o_colsq + 128;   // 256
    size_t o_T      = o_ss + 256;      // 128*64
    size_t o_Mm     = o_T + 128 * 64;  // 128*128

    float*    Hb    = ws + o_H;
    float*    Ob    = ws + o_O;
    float*    ai    = ws + o_ai;
    float*    aj    = ws + o_aj;
    unsigned* amax  = (unsigned*)(ws + o_amax);
    float*    den   = ws + o_den;
    float*    alpha = ws + o_alpha;
    int*      deg   = (int*)(ws + o_deg);
    int*      fill  = (int*)(ws + o_fill);
    int*      rowp  = (int*)(ws + o_rowptr);
    int*      srcc  = (int*)(ws + o_src);
    int*      dstc  = (int*)(ws + o_dst);
    int*      bsum  = (int*)(ws + o_bsum);
    int*      boff  = (int*)(ws + o_boff);
    float*    csum  = ws + o_colsum;
    float*    csq   = ws + o_colsq;
    float*    ss    = ws + o_ss;
    float*    Tm    = ws + o_T;
    float*    Mm    = ws + o_Mm;

    const int EB = (TE + 255) / 256;

    // ---- CSR by dst ----
    hipMemsetAsync(deg, 0, (size_t)N * 4, stream);
    k_deg<<<EB, 256, 0, stream>>>(ei, deg);
    k_scan1<<<SCAN_B, 256, 0, stream>>>(deg, bsum);
    k_scan2<<<1, 256, 0, stream>>>(bsum, boff, rowp);
    k_scan3<<<SCAN_B, 256, 0, stream>>>(deg, boff, rowp);
    hipMemsetAsync(fill, 0, (size_t)N * 4, stream);
    k_fill<<<EB, 256, 0, stream>>>(ei, rowp, fill, srcc, dstc);

    // ---- 3 GAT layers ----
    for (int l = 0; l < 3; l++) {
        const float* Xin = (l == 0) ? x : Ob;
        k_gemm<<<N / 16, 256, 0, stream>>>(Xin, W[l], Hb, ss, l > 0 ? 1 : 0);
        k_attdots<<<(N + 3) / 4, 256, 0, stream>>>(Hb, att[l], ai, aj);
        hipMemsetAsync(amax, 0, (size_t)2 * N * 4, stream);  // amax keys + den
        k_alpha_max<<<EB, 256, 0, stream>>>(srcc, dstc, ai, aj, alpha, amax);
        k_exp_den<<<EB, 256, 0, stream>>>(srcc, alpha, amax, den);
        k_aggregate<<<(N + 3) / 4, 256, 0, stream>>>(rowp, srcc, alpha, den, Hb, bb[l], Ob);
        hipMemsetAsync(csum, 0, 256 * 4, stream);            // colsum + colsq
        k_stats<<<256, 256, 0, stream>>>(Ob, csum, csq);
        k_bnfinal<<<1, 128, 0, stream>>>(csum, csq, gg[l], be[l], ss);
    }

    // ---- decoder ----
    k_T<<<32, 256, 0, stream>>>(P1, P2, Tm);
    k_M<<<64, 256, 0, stream>>>(Tm, P1, Mm);
    k_pred<<<1024, 128, 0, stream>>>(Ob, ss, drug, Mm, (float*)d_out);
}